// Round 15
// baseline (2104.416 us; speedup 1.0000x reference)
//
#include <hip/hip_runtime.h>

typedef __bf16 bf16x8 __attribute__((ext_vector_type(8)));
typedef float  f32x4  __attribute__((ext_vector_type(4)));
typedef int    i32x4  __attribute__((ext_vector_type(4)));
typedef __attribute__((address_space(3))) unsigned char lds_b;
typedef __attribute__((address_space(1))) const unsigned char glb_b;

#define LOG2E 1.4426950408889634f

__device__ __forceinline__ float rcp_(float x) { return __builtin_amdgcn_rcpf(x); }
__device__ __forceinline__ float ex2_(float x) { return __builtin_amdgcn_exp2f(x); }
__device__ __forceinline__ float bflo(unsigned u) { return __uint_as_float(u << 16); }
__device__ __forceinline__ float bfhi(unsigned u) { return __uint_as_float(u & 0xffff0000u); }
__device__ __forceinline__ void gll16(const void* g, void* l) {
  __builtin_amdgcn_global_load_lds((glb_b*)g, (lds_b*)l, 16, 0, 0);
}

// ---------------------------------------------------------------------------
// prep_wih: Wih rows in r''' order: r''' = (d>>2)*12 + gt*4 + (d&3) per dir.
// Rows+bias PRE-SCALED by -log2e (r,z) / -2log2e (n). bih fold: + bhh r,z.
// ---------------------------------------------------------------------------
__global__ __launch_bounds__(256) void prep_wih(
    const float* __restrict__ Wih, const float* __restrict__ bsrc, int Kin,
    __bf16* __restrict__ wih_o, float* __restrict__ bih_o)
{
  int R = blockIdx.x;                 // 0..1535
  int dir = R / 768, rp = R % 768;
  int q = rp / 12, rem = rp % 12, gt = rem >> 2, dlow = rem & 3;
  int d = q * 4 + dlow, g = gt * 256 + d;
  const float sc = (gt < 2) ? -LOG2E : (-2.0f * LOG2E);
  const float* src = Wih + ((size_t)dir * 768 + g) * Kin;
  __bf16* dst = wih_o + (size_t)R * Kin;
  for (int k = threadIdx.x; k < Kin; k += 256) dst[k] = (__bf16)(src[k] * sc);
  if (threadIdx.x == 0) {
    float bih = bsrc[(dir * 2 + 0) * 768 + g];
    float bhh = bsrc[(dir * 2 + 1) * 768 + g];
    bih_o[R] = (bih + (gt < 2 ? bhh : 0.0f)) * sc;
  }
}

// ---------------------------------------------------------------------------
// prep_whh: int8 quantization, per-16x16-row-tile scale (unchanged layout).
// ---------------------------------------------------------------------------
__global__ __launch_bounds__(256) void prep_whh(
    const float* __restrict__ Whh, signed char* __restrict__ wq,
    float* __restrict__ sws)
{
  __shared__ float red[256];
  int b = blockIdx.x;
  int gt = b % 3, dg = (b / 3) % 2, w = (b / 6) % 8, dir = b / 48;
  int t = threadIdx.x;
  int r16 = t >> 4, kb = (t & 15) * 16;
  int g = gt * 256 + w * 32 + dg * 16 + r16;
  const float* row = Whh + ((size_t)dir * 768 + g) * 256 + kb;
  float v[16]; float m = 0.f;
  #pragma unroll
  for (int j = 0; j < 16; ++j) { v[j] = row[j]; m = fmaxf(m, fabsf(v[j])); }
  red[t] = m; __syncthreads();
  for (int o = 128; o; o >>= 1) { if (t < o) red[t] = fmaxf(red[t], red[t + o]); __syncthreads(); }
  float scale = fmaxf(red[0], 1e-12f) / 127.f;
  if (t == 0) sws[((dir * 8 + w) * 2 + dg) * 3 + gt] = scale / 127.f;
  int ks2 = (t & 15) >> 2, lq = (t & 15) & 3;
  size_t base = ((size_t)((dir * 8 + w) * 24 + ks2 * 6 + dg * 3 + gt)) * 1024
              + (lq * 16 + r16) * 16;
  float inv = 1.f / scale;
  #pragma unroll
  for (int j = 0; j < 16; ++j) {
    int qv = (int)rintf(v[j] * inv);
    qv = qv > 127 ? 127 : (qv < -127 ? -127 : qv);
    wq[base + j] = (signed char)qv;
  }
}

// ---------------------------------------------------------------------------
// k_deq: ys int8 [16384][512] -> bf16 rows with stride ostride.
// ---------------------------------------------------------------------------
__global__ __launch_bounds__(256) void k_deq(
    const signed char* __restrict__ in, __bf16* __restrict__ out, int ostride)
{
  size_t i = ((size_t)blockIdx.x * 256 + threadIdx.x) * 8;
  int row = (int)(i >> 9), col = (int)(i & 511);
  uint2 v = *(const uint2*)(in + i);
  __bf16 ob[8];
  #pragma unroll
  for (int j = 0; j < 8; ++j) {
    unsigned wd = (j < 4) ? v.x : v.y;
    int sb = (int)(wd << (24 - 8 * (j & 3))) >> 24;
    ob[j] = (__bf16)((float)sb * (1.0f / 127.0f));
  }
  *(bf16x8*)(out + (size_t)row * ostride + col) = *(bf16x8*)ob;
}

// ---------------------------------------------------------------------------
// a[b,t] = c[b,t,:]·wc   and   e[b,j] = q[b,j,:]·wq    (one wave per dot)
// ---------------------------------------------------------------------------
__global__ __launch_bounds__(256) void k_dots(
    const float* __restrict__ c, const float* __restrict__ q,
    const float* __restrict__ Ws, float* __restrict__ a_g, float* __restrict__ e_g)
{
  const int wid = blockIdx.x * 4 + (threadIdx.x >> 6);
  const int lane = threadIdx.x & 63;
  const float* x; const float* wv; float* o;
  if (wid < 4096) { x = q + (size_t)wid * 512; wv = Ws + 512; o = e_g + wid; }
  else { int id = wid - 4096; x = c + (size_t)id * 512; wv = Ws; o = a_g + id; }
  float s = 0.f;
  #pragma unroll
  for (int i = 0; i < 8; ++i) s = fmaf(x[lane * 8 + i], wv[lane * 8 + i], s);
  #pragma unroll
  for (int off = 32; off; off >>= 1) s += __shfl_xor(s, off);
  if (lane == 0) *o = s;
}

// ---------------------------------------------------------------------------
// Fused attention main: per (b, t-half).
// ---------------------------------------------------------------------------
__global__ __launch_bounds__(512) void k_att_main(
    const float* __restrict__ c, const float* __restrict__ q,
    const float* __restrict__ Ws, const float* __restrict__ a_g,
    const float* __restrict__ e_g, float* __restrict__ smax_g,
    __bf16* __restrict__ G)
{
  constexpr int QSTR = 513;
  __shared__ float q_s[64 * QSTR];
  __shared__ float c_s[512], cw_s[512], sP[64], e_s[64], sred[512];
  const int b = blockIdx.y, th = blockIdx.x;
  const int tid = threadIdx.x;
  const float* qb = q + (size_t)b * 64 * 512;
  for (int i = tid; i < 64 * 512; i += 512) q_s[(i >> 9) * QSTR + (i & 511)] = qb[i];
  if (tid < 64) e_s[tid] = e_g[b * 64 + tid];
  __syncthreads();
  const int p = tid >> 6;
  const int j = tid & 63;
  for (int tt = 0; tt < 128; ++tt) {
    const int t = th * 128 + tt;
    float cv = c[((size_t)b * 256 + t) * 512 + tid];
    c_s[tid] = cv;
    cw_s[tid] = cv * Ws[1024 + tid];
    __syncthreads();
    {
      const float* qrow = &q_s[j * QSTR + p * 64];
      const float* cw = &cw_s[p * 64];
      float s = 0.f;
      #pragma unroll
      for (int i = 0; i < 64; ++i) s = fmaf(cw[i], qrow[i], s);
      sred[p * 64 + j] = s;
    }
    __syncthreads();
    if (tid < 64) {
      float s = sred[tid] + sred[64 + tid] + sred[128 + tid] + sred[192 + tid]
              + sred[256 + tid] + sred[320 + tid] + sred[384 + tid] + sred[448 + tid];
      s += a_g[b * 256 + t] + e_s[tid];
      float m = s;
      #pragma unroll
      for (int off = 32; off; off >>= 1) m = fmaxf(m, __shfl_xor(m, off));
      float e = __expf(s - m);
      float sum = e;
      #pragma unroll
      for (int off = 32; off; off >>= 1) sum += __shfl_xor(sum, off);
      sP[tid] = e / sum;
      if (tid == 0) smax_g[b * 256 + t] = m;
    }
    __syncthreads();
    {
      float acc = 0.f;
      #pragma unroll 8
      for (int jj = 0; jj < 64; ++jj) acc = fmaf(sP[jj], q_s[jj * QSTR + tid], acc);
      float cval = c_s[tid];
      __bf16* Gr = G + ((size_t)b * 256 + t) * 2560;
      Gr[tid]        = (__bf16)cval;
      Gr[512 + tid]  = (__bf16)acc;
      Gr[1024 + tid] = (__bf16)(cval * acc);
    }
    __syncthreads();
  }
}

// ---------------------------------------------------------------------------
// q2c tail
// ---------------------------------------------------------------------------
__global__ __launch_bounds__(256) void k_att_tail(
    const float* __restrict__ c, const float* __restrict__ smax_g,
    __bf16* __restrict__ G)
{
  __shared__ float w_s[256];
  __shared__ float red[8];
  const int b = blockIdx.x, tid = threadIdx.x;
  const int lane = tid & 63, wv = tid >> 6;
  float v = smax_g[b * 256 + tid];
  float m = v;
  #pragma unroll
  for (int off = 32; off; off >>= 1) m = fmaxf(m, __shfl_xor(m, off));
  if (lane == 0) red[wv] = m;
  __syncthreads();
  m = fmaxf(fmaxf(red[0], red[1]), fmaxf(red[2], red[3]));
  float e = __expf(v - m);
  float s = e;
  #pragma unroll
  for (int off = 32; off; off >>= 1) s += __shfl_xor(s, off);
  if (lane == 0) red[4 + wv] = s;
  __syncthreads();
  s = red[4] + red[5] + red[6] + red[7];
  w_s[tid] = e / s;
  __syncthreads();
  float q0 = 0.f, q1 = 0.f;
  for (int t = 0; t < 256; ++t) {
    const float* cr = c + ((size_t)b * 256 + t) * 512;
    q0 = fmaf(w_s[t], cr[tid], q0);
    q1 = fmaf(w_s[t], cr[tid + 256], q1);
  }
  for (int t = 0; t < 256; ++t) {
    const float* cr = c + ((size_t)b * 256 + t) * 512;
    __bf16* Gr = G + ((size_t)b * 256 + t) * 2560 + 1536;
    Gr[tid]       = (__bf16)(cr[tid] * q0);
    Gr[tid + 256] = (__bf16)(cr[tid + 256] * q1);
  }
}

// ---------------------------------------------------------------------------
// GEMM v5: 256x128, 8 waves, BK=32, 3-deep counted-vmcnt pipeline (R14) +
// T2 both-sides XOR swizzle (slot = (lq + ((row>>1)&3))&3 -> 2-way free;
// source-side inverse on the gll16 global column, dest stays linear) +
// T1 bijective XCD swizzle (768 WGs, 96 tiles/XCD) + T5 setprio on MFMAs.
// ---------------------------------------------------------------------------
#define GEMM_LDS_BYTES ((3 * 8192 + 3 * 4096) * 2)
__global__ __launch_bounds__(512) void gemm_bt(
    const __bf16* __restrict__ A, int lda,
    const __bf16* __restrict__ Bw, const float* __restrict__ bias,
    __bf16* __restrict__ C, int K)
{
  extern __shared__ __align__(16) __bf16 gsm[];
  __bf16* As = gsm;              // 3 x [256][32] (row-major, slot-swizzled)
  __bf16* Bs = gsm + 3 * 8192;   // 3 x [128][32]
  const int tid = threadIdx.x;
  const int lane = tid & 63, w = tid >> 6;       // w 0..7
  const int l15 = lane & 15, lq = lane >> 4;
  const int wm = w >> 1, wn = w & 1;             // 4m x 2n wave grid
  // T1: bijective XCD remap (nwg=768, 768%8==0 -> 96 contiguous tiles/XCD)
  const int lin = blockIdx.x + 64 * blockIdx.y;
  const int nlin = (lin & 7) * 96 + (lin >> 3);
  const size_t bm = (size_t)(nlin & 63) * 256;
  const size_t bn = (size_t)(nlin >> 6) * 128;
  const int srow = lane >> 2;                     // stage: lane -> row-in-16
  f32x4 acc[4][4] = {};
  const int nkt = K >> 5;

  // T2 source-side swizzle: phys slot = lane&3 at dest; logical col block
  // lslot = ((lane&3) - ((row>>1)&3)) & 3 ; global col = ko + lslot*8
  #define G_STAGE(BI, KT) do { const int ko_ = (KT) * 32;                        \
    _Pragma("unroll")                                                            \
    for (int j_ = 0; j_ < 2; ++j_) {                                             \
      const int rb_ = (j_ * 8 + w) * 16;                                         \
      const int arow_ = rb_ + srow;                                              \
      const int acol_ = ((((lane & 3) - ((arow_ >> 1) & 3)) & 3) * 8);           \
      gll16(A + (bm + arow_) * (size_t)lda + ko_ + acol_,                        \
            &As[(BI) * 8192 + rb_ * 32]);                                        \
    }                                                                            \
    { const int rb_ = w * 16;                                                    \
      const int brow_ = rb_ + srow;                                              \
      const int bcol_ = ((((lane & 3) - ((brow_ >> 1) & 3)) & 3) * 8);           \
      gll16(Bw + (bn + brow_) * (size_t)K + ko_ + bcol_,                         \
            &Bs[(BI) * 4096 + rb_ * 32]); }                                      \
  } while (0)

  G_STAGE(0, 0);
  G_STAGE(1, 1);
  asm volatile("s_waitcnt vmcnt(3)" ::: "memory");   // buf0 done; buf1 in flight
  __builtin_amdgcn_s_barrier();

  int cb = 0, nb = 2;
  for (int kt = 0; kt < nkt; ++kt) {
    if (kt + 2 < nkt) G_STAGE(nb, kt + 2);
    const __bf16* Ab = &As[cb * 8192];
    const __bf16* Bb = &Bs[cb * 4096];
    bf16x8 af[4], bfv[4];
    #pragma unroll
    for (int f = 0; f < 4; ++f) {
      const int ar = wm * 64 + f * 16 + l15;
      const int br = wn * 64 + f * 16 + l15;
      af[f]  = *(const bf16x8*)&Ab[ar * 32 + (((lq + ((ar >> 1) & 3)) & 3) * 8)];
      bfv[f] = *(const bf16x8*)&Bb[br * 32 + (((lq + ((br >> 1) & 3)) & 3) * 8)];
    }
    __builtin_amdgcn_s_setprio(1);
    #pragma unroll
    for (int fm = 0; fm < 4; ++fm)
      #pragma unroll
      for (int fn = 0; fn < 4; ++fn)
        acc[fm][fn] = __builtin_amdgcn_mfma_f32_16x16x32_bf16(af[fm], bfv[fn], acc[fm][fn], 0, 0, 0);
    __builtin_amdgcn_s_setprio(0);
    if (kt + 1 < nkt) {
      if (kt + 2 < nkt) asm volatile("s_waitcnt vmcnt(3)" ::: "memory");
      else              asm volatile("s_waitcnt vmcnt(0)" ::: "memory");
      __builtin_amdgcn_s_barrier();
    }
    cb = (cb == 2) ? 0 : cb + 1;
    nb = (nb == 2) ? 0 : nb + 1;
  }
  #undef G_STAGE

  float bv[4];
  #pragma unroll
  for (int fn = 0; fn < 4; ++fn) bv[fn] = bias[bn + wn * 64 + fn * 16 + l15];
  #pragma unroll
  for (int fm = 0; fm < 4; ++fm)
    #pragma unroll
    for (int fn = 0; fn < 4; ++fn)
      #pragma unroll
      for (int r = 0; r < 4; ++r) {
        size_t row = bm + wm * 64 + fm * 16 + lq * 4 + r;
        size_t col = bn + wn * 64 + fn * 16 + l15;
        C[row * 1536 + col] = (__bf16)(acc[fm][fn][r] + bv[fn]);
      }
}

// ---------------------------------------------------------------------------
// GRU recurrence v12 (unchanged; trans+VALU issue-bound floor ~352us).
// ---------------------------------------------------------------------------
#define GRU_HST 272
#define GRU_HB (16 * GRU_HST)
__global__ __launch_bounds__(1024) void gru_rec(
    const __bf16* __restrict__ gi, const signed char* __restrict__ wq,
    const float* __restrict__ sws, const float* __restrict__ bsrc,
    signed char* __restrict__ ys_i8, float* __restrict__ out_final)
{
  __shared__ __align__(16) signed char hl[2 * GRU_HB];   // 8.7 KB
  const int tid = threadIdx.x;
  const int w16 = tid >> 6, lane = tid & 63;
  const int l15 = lane & 15, lq = lane >> 4;
  const int wold = w16 >> 1, dgw = w16 & 1;
  const int dir = blockIdx.y;
  const int b0 = blockIdx.x * 16;

  for (int i = tid; i < 2 * GRU_HB; i += 1024) hl[i] = 0;

  const signed char* wbase0 = wq + (size_t)(dir * 8 + wold) * 24 * 1024;
  i32x4 wr[12];
  #pragma unroll
  for (int j = 0; j < 12; ++j) {
    int oc = (j / 3) * 6 + dgw * 3 + (j % 3);
    wr[j] = *(const i32x4*)(wbase0 + oc * 1024 + lane * 16);
  }

  float f_[3];
  #pragma unroll
  for (int gt = 0; gt < 3; ++gt)
    f_[gt] = sws[((dir * 8 + wold) * 2 + dgw) * 3 + gt]
           * ((gt == 2) ? (-2.0f * LOG2E) : -LOG2E);
  float bhn[4];
  #pragma unroll
  for (int r = 0; r < 4; ++r)
    bhn[r] = bsrc[(dir * 2 + 1) * 768 + 512 + w16 * 16 + lq * 4 + r]
           * (-2.0f * LOG2E);

  const __bf16* gib = gi + ((size_t)(b0 + l15) * 256) * 1536 + dir * 768
                    + (w16 * 4 + lq) * 12;
  const int yrow = tid >> 6, ycol = (tid & 63) * 4;

  float hprev[4] = {0.f, 0.f, 0.f, 0.f};
  int cur = 0;
  __syncthreads();

  uint2 gA[3], gB[3];
  #define GI_LOAD(BUF, SS) do { if ((SS) < 256) {                               \
      const int tt_ = dir ? (255 - (SS)) : (SS);                                \
      const __bf16* gp_ = gib + (size_t)tt_ * 1536;                             \
      BUF[0] = *(const uint2*)(gp_);                                            \
      BUF[1] = *(const uint2*)(gp_ + 4);                                        \
      BUF[2] = *(const uint2*)(gp_ + 8); } } while (0)
  GI_LOAD(gA, 0);
  GI_LOAD(gB, 1);

  #define GRU_STEP(S, BUF) do {                                                 \
    const int t = dir ? (255 - (S)) : (S);                                      \
    i32x4 acc[3] = {};                                                          \
    const signed char* hb_ = hl + cur * GRU_HB + l15 * GRU_HST;                 \
    _Pragma("unroll")                                                           \
    for (int ks = 0; ks < 4; ++ks) {                                            \
      i32x4 hf = *(const i32x4*)(hb_ + ks * 64 + lq * 16);                      \
      _Pragma("unroll")                                                         \
      for (int gt = 0; gt < 3; ++gt)                                            \
        acc[gt] = __builtin_amdgcn_mfma_i32_16x16x64_i8(wr[ks * 3 + gt], hf, acc[gt], 0, 0, 0); \
    }                                                                           \
    unsigned pk = 0;                                                            \
    _Pragma("unroll")                                                           \
    for (int r = 0; r < 4; ++r) {                                               \
      unsigned x0 = (r < 2) ? BUF[0].x : BUF[0].y;                              \
      unsigned x1 = (r < 2) ? BUF[1].x : BUF[1].y;                              \
      unsigned x2 = (r < 2) ? BUF[2].x : BUF[2].y;                              \
      float ir  = (r & 1) ? bfhi(x0) : bflo(x0);                                \
      float iz  = (r & 1) ? bfhi(x1) : bflo(x1);                                \
      float in_ = (r & 1) ? bfhi(x2) : bflo(x2);                                \
      float aR = fmaf((float)acc[0][r], f_[0], ir);                             \
      float rg = rcp_(1.0f + ex2_(aR));                                         \
      float aZ = fmaf((float)acc[1][r], f_[1], iz);                             \
      float zg = rcp_(1.0f + ex2_(aZ));                                         \
      float tN = fmaf((float)acc[2][r], f_[2], bhn[r]);                         \
      float aN = fmaf(rg, tN, in_);                                             \
      float ng = fmaf(2.0f, rcp_(1.0f + ex2_(aN)), -1.0f);                      \
      float h = ng + zg * (hprev[r] - ng);                                      \
      hprev[r] = h;                                                             \
      unsigned byte = __float_as_uint(fmaf(h, 127.0f, 12582912.0f)) & 0xffu;    \
      pk |= byte << (8 * r);                                                    \
    }                                                                           \
    *(unsigned*)&hl[(cur ^ 1) * GRU_HB + l15 * GRU_HST + w16 * 16 + lq * 4] = pk; \
    GI_LOAD(BUF, (S) + 2);                                                      \
    asm volatile("s_waitcnt lgkmcnt(0)\n\ts_barrier" ::: "memory");             \
    if (ys_i8) {                                                                \
      unsigned v = *(const unsigned*)&hl[(cur ^ 1) * GRU_HB + yrow * GRU_HST + ycol]; \
      *(unsigned*)&ys_i8[(((size_t)(b0 + yrow) * 256 + t) * 512) + dir * 256 + ycol] = v; \
    }                                                                           \
    cur ^= 1;                                                                   \
  } while (0)

  for (int s = 0; s < 256; s += 2) {
    GRU_STEP(s, gA);
    GRU_STEP(s + 1, gB);
  }

  if (!ys_i8) {
    #pragma unroll
    for (int r = 0; r < 4; ++r)
      out_final[(size_t)(b0 + l15) * 512 + (dir ? 0 : 256) + w16 * 16 + lq * 4 + r]
          = hprev[r];
  }
  #undef GRU_STEP
  #undef GI_LOAD
}

// ---------------------------------------------------------------------------
extern "C" void kernel_launch(void* const* d_in, const int* in_sizes, int n_in,
                              void* d_out, int out_size, void* d_ws, size_t ws_size,
                              hipStream_t stream) {
  (void)in_sizes; (void)n_in; (void)out_size; (void)ws_size;
  const float* c  = (const float*)d_in[0];
  const float* q  = (const float*)d_in[1];
  const float* Ws = (const float*)d_in[4];
  const float* w_ih[4] = { (const float*)d_in[5], (const float*)d_in[8],
                           (const float*)d_in[11], (const float*)d_in[14] };
  const float* w_hh[4] = { (const float*)d_in[6], (const float*)d_in[9],
                           (const float*)d_in[12], (const float*)d_in[15] };
  const float* b_l[4]  = { (const float*)d_in[7], (const float*)d_in[10],
                           (const float*)d_in[13], (const float*)d_in[16] };
  const int Kin[4] = {2048, 512, 2560, 512};

  static int lds_set = 0;
  if (!lds_set) {
    hipFuncSetAttribute((const void*)gemm_bt,
                        hipFuncAttributeMaxDynamicSharedMemorySize, GEMM_LDS_BYTES);
    lds_set = 1;
  }

  char* ws = (char*)d_ws;
  size_t off = 0;
  auto alloc = [&](size_t bytes) -> void* {
    void* p = ws + off; off += (bytes + 255) & ~(size_t)255; return p;
  };
  __bf16* Gbuf = (__bf16*)alloc((size_t)16384 * 2560 * 2);  // [G | M] bf16
  __bf16* gi   = (__bf16*)alloc((size_t)16384 * 1536 * 2);  // r'''-packed bf16
  __bf16* m0   = (__bf16*)alloc((size_t)16384 * 512 * 2);
  __bf16* r0   = (__bf16*)alloc((size_t)16384 * 512 * 2);
  signed char* ys8 = (signed char*)alloc((size_t)16384 * 512);
  __bf16* wihp[4]; signed char* wqp[4]; float* bihp[4]; float* swsp[4];
  for (int l = 0; l < 4; ++l) {
    wihp[l] = (__bf16*)alloc((size_t)1536 * Kin[l] * 2);
    wqp[l]  = (signed char*)alloc((size_t)1536 * 256);
    bihp[l] = (float*)alloc(1536 * 4);
    swsp[l] = (float*)alloc(96 * 4);
  }
  float* e_g  = (float*)alloc(4096 * 4);
  float* a_g  = (float*)alloc(16384 * 4);
  float* smax = (float*)alloc(16384 * 4);

  for (int l = 0; l < 4; ++l) {
    prep_wih<<<1536, 256, 0, stream>>>(w_ih[l], b_l[l], Kin[l], wihp[l], bihp[l]);
    prep_whh<<<96, 256, 0, stream>>>(w_hh[l], wqp[l], swsp[l]);
  }
  k_dots<<<5120, 256, 0, stream>>>(c, q, Ws, a_g, e_g);
  k_att_main<<<dim3(2, 64), 512, 0, stream>>>(c, q, Ws, a_g, e_g, smax, Gbuf);
  k_att_tail<<<64, 256, 0, stream>>>(c, smax, Gbuf);

  // layer mod0: G(2048) -> m0
  gemm_bt<<<dim3(64, 12), 512, GEMM_LDS_BYTES, stream>>>(Gbuf, 2560, wihp[0], bihp[0], gi, 2048);
  gru_rec<<<dim3(4, 2), 1024, 0, stream>>>(gi, wqp[0], swsp[0], b_l[0], ys8, nullptr);
  k_deq<<<4096, 256, 0, stream>>>(ys8, m0, 512);
  // layer mod1: m0(512) -> M (into Gbuf cols 2048:2560)
  gemm_bt<<<dim3(64, 12), 512, GEMM_LDS_BYTES, stream>>>(m0, 512, wihp[1], bihp[1], gi, 512);
  gru_rec<<<dim3(4, 2), 1024, 0, stream>>>(gi, wqp[1], swsp[1], b_l[1], ys8, nullptr);
  k_deq<<<4096, 256, 0, stream>>>(ys8, Gbuf + 2048, 2560);
  // layer rep0: [G|M](2560) -> r0
  gemm_bt<<<dim3(64, 12), 512, GEMM_LDS_BYTES, stream>>>(Gbuf, 2560, wihp[2], bihp[2], gi, 2560);
  gru_rec<<<dim3(4, 2), 1024, 0, stream>>>(gi, wqp[2], swsp[2], b_l[2], ys8, nullptr);
  k_deq<<<4096, 256, 0, stream>>>(ys8, r0, 512);
  // layer rep1: r0(512) -> final h only
  gemm_bt<<<dim3(64, 12), 512, GEMM_LDS_BYTES, stream>>>(r0, 512, wihp[3], bihp[3], gi, 512);
  gru_rec<<<dim3(4, 2), 1024, 0, stream>>>(gi, wqp[3], swsp[3], b_l[3], nullptr, (float*)d_out);
}

// Round 16
// 2029.840 us; speedup vs baseline: 1.0367x; 1.0367x over previous
//
#include <hip/hip_runtime.h>

typedef __bf16 bf16x8 __attribute__((ext_vector_type(8)));
typedef float  f32x4  __attribute__((ext_vector_type(4)));
typedef int    i32x4  __attribute__((ext_vector_type(4)));
typedef __attribute__((address_space(3))) unsigned char lds_b;
typedef __attribute__((address_space(1))) const unsigned char glb_b;

#define LOG2E 1.4426950408889634f

__device__ __forceinline__ float rcp_(float x) { return __builtin_amdgcn_rcpf(x); }
__device__ __forceinline__ float ex2_(float x) { return __builtin_amdgcn_exp2f(x); }
__device__ __forceinline__ float bflo(unsigned u) { return __uint_as_float(u << 16); }
__device__ __forceinline__ float bfhi(unsigned u) { return __uint_as_float(u & 0xffff0000u); }
__device__ __forceinline__ void gll16(const void* g, void* l) {
  __builtin_amdgcn_global_load_lds((glb_b*)g, (lds_b*)l, 16, 0, 0);
}

// ---------------------------------------------------------------------------
// prep_wih: Wih rows in r''' order: r''' = (d>>2)*12 + gt*4 + (d&3) per dir.
// Rows+bias PRE-SCALED by -log2e (r,z) / -2log2e (n). bih fold: + bhh r,z.
// ---------------------------------------------------------------------------
__global__ __launch_bounds__(256) void prep_wih(
    const float* __restrict__ Wih, const float* __restrict__ bsrc, int Kin,
    __bf16* __restrict__ wih_o, float* __restrict__ bih_o)
{
  int R = blockIdx.x;                 // 0..1535
  int dir = R / 768, rp = R % 768;
  int q = rp / 12, rem = rp % 12, gt = rem >> 2, dlow = rem & 3;
  int d = q * 4 + dlow, g = gt * 256 + d;
  const float sc = (gt < 2) ? -LOG2E : (-2.0f * LOG2E);
  const float* src = Wih + ((size_t)dir * 768 + g) * Kin;
  __bf16* dst = wih_o + (size_t)R * Kin;
  for (int k = threadIdx.x; k < Kin; k += 256) dst[k] = (__bf16)(src[k] * sc);
  if (threadIdx.x == 0) {
    float bih = bsrc[(dir * 2 + 0) * 768 + g];
    float bhh = bsrc[(dir * 2 + 1) * 768 + g];
    bih_o[R] = (bih + (gt < 2 ? bhh : 0.0f)) * sc;
  }
}

// ---------------------------------------------------------------------------
// prep_whh: int8 quantization, per-16x16-row-tile scale (unchanged layout).
// ---------------------------------------------------------------------------
__global__ __launch_bounds__(256) void prep_whh(
    const float* __restrict__ Whh, signed char* __restrict__ wq,
    float* __restrict__ sws)
{
  __shared__ float red[256];
  int b = blockIdx.x;
  int gt = b % 3, dg = (b / 3) % 2, w = (b / 6) % 8, dir = b / 48;
  int t = threadIdx.x;
  int r16 = t >> 4, kb = (t & 15) * 16;
  int g = gt * 256 + w * 32 + dg * 16 + r16;
  const float* row = Whh + ((size_t)dir * 768 + g) * 256 + kb;
  float v[16]; float m = 0.f;
  #pragma unroll
  for (int j = 0; j < 16; ++j) { v[j] = row[j]; m = fmaxf(m, fabsf(v[j])); }
  red[t] = m; __syncthreads();
  for (int o = 128; o; o >>= 1) { if (t < o) red[t] = fmaxf(red[t], red[t + o]); __syncthreads(); }
  float scale = fmaxf(red[0], 1e-12f) / 127.f;
  if (t == 0) sws[((dir * 8 + w) * 2 + dg) * 3 + gt] = scale / 127.f;
  int ks2 = (t & 15) >> 2, lq = (t & 15) & 3;
  size_t base = ((size_t)((dir * 8 + w) * 24 + ks2 * 6 + dg * 3 + gt)) * 1024
              + (lq * 16 + r16) * 16;
  float inv = 1.f / scale;
  #pragma unroll
  for (int j = 0; j < 16; ++j) {
    int qv = (int)rintf(v[j] * inv);
    qv = qv > 127 ? 127 : (qv < -127 ? -127 : qv);
    wq[base + j] = (signed char)qv;
  }
}

// ---------------------------------------------------------------------------
// k_deq: ys int8 [16384][512] -> bf16 rows with stride ostride.
// ---------------------------------------------------------------------------
__global__ __launch_bounds__(256) void k_deq(
    const signed char* __restrict__ in, __bf16* __restrict__ out, int ostride)
{
  size_t i = ((size_t)blockIdx.x * 256 + threadIdx.x) * 8;
  int row = (int)(i >> 9), col = (int)(i & 511);
  uint2 v = *(const uint2*)(in + i);
  __bf16 ob[8];
  #pragma unroll
  for (int j = 0; j < 8; ++j) {
    unsigned wd = (j < 4) ? v.x : v.y;
    int sb = (int)(wd << (24 - 8 * (j & 3))) >> 24;
    ob[j] = (__bf16)((float)sb * (1.0f / 127.0f));
  }
  *(bf16x8*)(out + (size_t)row * ostride + col) = *(bf16x8*)ob;
}

// ---------------------------------------------------------------------------
// a[b,t] = c[b,t,:]·wc   and   e[b,j] = q[b,j,:]·wq    (one wave per dot)
// ---------------------------------------------------------------------------
__global__ __launch_bounds__(256) void k_dots(
    const float* __restrict__ c, const float* __restrict__ q,
    const float* __restrict__ Ws, float* __restrict__ a_g, float* __restrict__ e_g)
{
  const int wid = blockIdx.x * 4 + (threadIdx.x >> 6);
  const int lane = threadIdx.x & 63;
  const float* x; const float* wv; float* o;
  if (wid < 4096) { x = q + (size_t)wid * 512; wv = Ws + 512; o = e_g + wid; }
  else { int id = wid - 4096; x = c + (size_t)id * 512; wv = Ws; o = a_g + id; }
  float s = 0.f;
  #pragma unroll
  for (int i = 0; i < 8; ++i) s = fmaf(x[lane * 8 + i], wv[lane * 8 + i], s);
  #pragma unroll
  for (int off = 32; off; off >>= 1) s += __shfl_xor(s, off);
  if (lane == 0) *o = s;
}

// ---------------------------------------------------------------------------
// Fused attention main: per (b, t-half).
// ---------------------------------------------------------------------------
__global__ __launch_bounds__(512) void k_att_main(
    const float* __restrict__ c, const float* __restrict__ q,
    const float* __restrict__ Ws, const float* __restrict__ a_g,
    const float* __restrict__ e_g, float* __restrict__ smax_g,
    __bf16* __restrict__ G)
{
  constexpr int QSTR = 513;
  __shared__ float q_s[64 * QSTR];
  __shared__ float c_s[512], cw_s[512], sP[64], e_s[64], sred[512];
  const int b = blockIdx.y, th = blockIdx.x;
  const int tid = threadIdx.x;
  const float* qb = q + (size_t)b * 64 * 512;
  for (int i = tid; i < 64 * 512; i += 512) q_s[(i >> 9) * QSTR + (i & 511)] = qb[i];
  if (tid < 64) e_s[tid] = e_g[b * 64 + tid];
  __syncthreads();
  const int p = tid >> 6;
  const int j = tid & 63;
  for (int tt = 0; tt < 128; ++tt) {
    const int t = th * 128 + tt;
    float cv = c[((size_t)b * 256 + t) * 512 + tid];
    c_s[tid] = cv;
    cw_s[tid] = cv * Ws[1024 + tid];
    __syncthreads();
    {
      const float* qrow = &q_s[j * QSTR + p * 64];
      const float* cw = &cw_s[p * 64];
      float s = 0.f;
      #pragma unroll
      for (int i = 0; i < 64; ++i) s = fmaf(cw[i], qrow[i], s);
      sred[p * 64 + j] = s;
    }
    __syncthreads();
    if (tid < 64) {
      float s = sred[tid] + sred[64 + tid] + sred[128 + tid] + sred[192 + tid]
              + sred[256 + tid] + sred[320 + tid] + sred[384 + tid] + sred[448 + tid];
      s += a_g[b * 256 + t] + e_s[tid];
      float m = s;
      #pragma unroll
      for (int off = 32; off; off >>= 1) m = fmaxf(m, __shfl_xor(m, off));
      float e = __expf(s - m);
      float sum = e;
      #pragma unroll
      for (int off = 32; off; off >>= 1) sum += __shfl_xor(sum, off);
      sP[tid] = e / sum;
      if (tid == 0) smax_g[b * 256 + t] = m;
    }
    __syncthreads();
    {
      float acc = 0.f;
      #pragma unroll 8
      for (int jj = 0; jj < 64; ++jj) acc = fmaf(sP[jj], q_s[jj * QSTR + tid], acc);
      float cval = c_s[tid];
      __bf16* Gr = G + ((size_t)b * 256 + t) * 2560;
      Gr[tid]        = (__bf16)cval;
      Gr[512 + tid]  = (__bf16)acc;
      Gr[1024 + tid] = (__bf16)(cval * acc);
    }
    __syncthreads();
  }
}

// ---------------------------------------------------------------------------
// q2c tail
// ---------------------------------------------------------------------------
__global__ __launch_bounds__(256) void k_att_tail(
    const float* __restrict__ c, const float* __restrict__ smax_g,
    __bf16* __restrict__ G)
{
  __shared__ float w_s[256];
  __shared__ float red[8];
  const int b = blockIdx.x, tid = threadIdx.x;
  const int lane = tid & 63, wv = tid >> 6;
  float v = smax_g[b * 256 + tid];
  float m = v;
  #pragma unroll
  for (int off = 32; off; off >>= 1) m = fmaxf(m, __shfl_xor(m, off));
  if (lane == 0) red[wv] = m;
  __syncthreads();
  m = fmaxf(fmaxf(red[0], red[1]), fmaxf(red[2], red[3]));
  float e = __expf(v - m);
  float s = e;
  #pragma unroll
  for (int off = 32; off; off >>= 1) s += __shfl_xor(s, off);
  if (lane == 0) red[4 + wv] = s;
  __syncthreads();
  s = red[4] + red[5] + red[6] + red[7];
  w_s[tid] = e / s;
  __syncthreads();
  float q0 = 0.f, q1 = 0.f;
  for (int t = 0; t < 256; ++t) {
    const float* cr = c + ((size_t)b * 256 + t) * 512;
    q0 = fmaf(w_s[t], cr[tid], q0);
    q1 = fmaf(w_s[t], cr[tid + 256], q1);
  }
  for (int t = 0; t < 256; ++t) {
    const float* cr = c + ((size_t)b * 256 + t) * 512;
    __bf16* Gr = G + ((size_t)b * 256 + t) * 2560 + 1536;
    Gr[tid]       = (__bf16)(cr[tid] * q0);
    Gr[tid + 256] = (__bf16)(cr[tid + 256] * q1);
  }
}

// ---------------------------------------------------------------------------
// GEMM v4 (reverted to R14 best-measured): 256x128, 8 waves, BK=32, 3-deep
// counted-vmcnt pipeline, linear LDS, natural grid. R15's swizzle/XCD/setprio
// bundle measured -73us -> dropped.
// ---------------------------------------------------------------------------
#define GEMM_LDS_BYTES ((3 * 8192 + 3 * 4096) * 2)
__global__ __launch_bounds__(512) void gemm_bt(
    const __bf16* __restrict__ A, int lda,
    const __bf16* __restrict__ Bw, const float* __restrict__ bias,
    __bf16* __restrict__ C, int K)
{
  extern __shared__ __align__(16) __bf16 gsm[];
  __bf16* As = gsm;              // 3 x [256][32]
  __bf16* Bs = gsm + 3 * 8192;   // 3 x [128][32]
  const int tid = threadIdx.x;
  const int lane = tid & 63, w = tid >> 6;       // w 0..7
  const int l15 = lane & 15, lq = lane >> 4;
  const int wm = w >> 1, wn = w & 1;             // 4m x 2n wave grid
  const size_t bm = (size_t)blockIdx.x * 256;
  const size_t bn = (size_t)blockIdx.y * 128;
  const int srow = lane >> 2, scol = (lane & 3) * 8;
  f32x4 acc[4][4] = {};
  const int nkt = K >> 5;

  #define G_STAGE(BI, KT) do { const int ko_ = (KT) * 32;                        \
    _Pragma("unroll")                                                            \
    for (int j_ = 0; j_ < 2; ++j_) {                                             \
      const int rb_ = (j_ * 8 + w) * 16;                                         \
      gll16(A + (bm + rb_ + srow) * (size_t)lda + ko_ + scol,                    \
            &As[(BI) * 8192 + rb_ * 32]);                                        \
    }                                                                            \
    { const int rb_ = w * 16;                                                    \
      gll16(Bw + (bn + rb_ + srow) * (size_t)K + ko_ + scol,                     \
            &Bs[(BI) * 4096 + rb_ * 32]); }                                      \
  } while (0)

  G_STAGE(0, 0);
  G_STAGE(1, 1);
  asm volatile("s_waitcnt vmcnt(3)" ::: "memory");   // buf0 done; buf1 in flight
  __builtin_amdgcn_s_barrier();

  int cb = 0, nb = 2;
  for (int kt = 0; kt < nkt; ++kt) {
    if (kt + 2 < nkt) G_STAGE(nb, kt + 2);
    const __bf16* Ab = &As[cb * 8192];
    const __bf16* Bb = &Bs[cb * 4096];
    bf16x8 af[4], bfv[4];
    #pragma unroll
    for (int f = 0; f < 4; ++f) {
      af[f]  = *(const bf16x8*)&Ab[(wm * 64 + f * 16 + l15) * 32 + lq * 8];
      bfv[f] = *(const bf16x8*)&Bb[(wn * 64 + f * 16 + l15) * 32 + lq * 8];
    }
    #pragma unroll
    for (int fm = 0; fm < 4; ++fm)
      #pragma unroll
      for (int fn = 0; fn < 4; ++fn)
        acc[fm][fn] = __builtin_amdgcn_mfma_f32_16x16x32_bf16(af[fm], bfv[fn], acc[fm][fn], 0, 0, 0);
    if (kt + 1 < nkt) {
      if (kt + 2 < nkt) asm volatile("s_waitcnt vmcnt(3)" ::: "memory");
      else              asm volatile("s_waitcnt vmcnt(0)" ::: "memory");
      __builtin_amdgcn_s_barrier();
    }
    cb = (cb == 2) ? 0 : cb + 1;
    nb = (nb == 2) ? 0 : nb + 1;
  }
  #undef G_STAGE

  float bv[4];
  #pragma unroll
  for (int fn = 0; fn < 4; ++fn) bv[fn] = bias[bn + wn * 64 + fn * 16 + l15];
  #pragma unroll
  for (int fm = 0; fm < 4; ++fm)
    #pragma unroll
    for (int fn = 0; fn < 4; ++fn)
      #pragma unroll
      for (int r = 0; r < 4; ++r) {
        size_t row = bm + wm * 64 + fm * 16 + lq * 4 + r;
        size_t col = bn + wn * 64 + fn * 16 + l15;
        C[row * 1536 + col] = (__bf16)(acc[fm][fn][r] + bv[fn]);
      }
}

// ---------------------------------------------------------------------------
// GRU recurrence v12 (unchanged; trans+VALU issue-bound floor ~352us).
// ---------------------------------------------------------------------------
#define GRU_HST 272
#define GRU_HB (16 * GRU_HST)
__global__ __launch_bounds__(1024) void gru_rec(
    const __bf16* __restrict__ gi, const signed char* __restrict__ wq,
    const float* __restrict__ sws, const float* __restrict__ bsrc,
    signed char* __restrict__ ys_i8, float* __restrict__ out_final)
{
  __shared__ __align__(16) signed char hl[2 * GRU_HB];   // 8.7 KB
  const int tid = threadIdx.x;
  const int w16 = tid >> 6, lane = tid & 63;
  const int l15 = lane & 15, lq = lane >> 4;
  const int wold = w16 >> 1, dgw = w16 & 1;
  const int dir = blockIdx.y;
  const int b0 = blockIdx.x * 16;

  for (int i = tid; i < 2 * GRU_HB; i += 1024) hl[i] = 0;

  const signed char* wbase0 = wq + (size_t)(dir * 8 + wold) * 24 * 1024;
  i32x4 wr[12];
  #pragma unroll
  for (int j = 0; j < 12; ++j) {
    int oc = (j / 3) * 6 + dgw * 3 + (j % 3);
    wr[j] = *(const i32x4*)(wbase0 + oc * 1024 + lane * 16);
  }

  float f_[3];
  #pragma unroll
  for (int gt = 0; gt < 3; ++gt)
    f_[gt] = sws[((dir * 8 + wold) * 2 + dgw) * 3 + gt]
           * ((gt == 2) ? (-2.0f * LOG2E) : -LOG2E);
  float bhn[4];
  #pragma unroll
  for (int r = 0; r < 4; ++r)
    bhn[r] = bsrc[(dir * 2 + 1) * 768 + 512 + w16 * 16 + lq * 4 + r]
           * (-2.0f * LOG2E);

  const __bf16* gib = gi + ((size_t)(b0 + l15) * 256) * 1536 + dir * 768
                    + (w16 * 4 + lq) * 12;
  const int yrow = tid >> 6, ycol = (tid & 63) * 4;

  float hprev[4] = {0.f, 0.f, 0.f, 0.f};
  int cur = 0;
  __syncthreads();

  uint2 gA[3], gB[3];
  #define GI_LOAD(BUF, SS) do { if ((SS) < 256) {                               \
      const int tt_ = dir ? (255 - (SS)) : (SS);                                \
      const __bf16* gp_ = gib + (size_t)tt_ * 1536;                             \
      BUF[0] = *(const uint2*)(gp_);                                            \
      BUF[1] = *(const uint2*)(gp_ + 4);                                        \
      BUF[2] = *(const uint2*)(gp_ + 8); } } while (0)
  GI_LOAD(gA, 0);
  GI_LOAD(gB, 1);

  #define GRU_STEP(S, BUF) do {                                                 \
    const int t = dir ? (255 - (S)) : (S);                                      \
    i32x4 acc[3] = {};                                                          \
    const signed char* hb_ = hl + cur * GRU_HB + l15 * GRU_HST;                 \
    _Pragma("unroll")                                                           \
    for (int ks = 0; ks < 4; ++ks) {                                            \
      i32x4 hf = *(const i32x4*)(hb_ + ks * 64 + lq * 16);                      \
      _Pragma("unroll")                                                         \
      for (int gt = 0; gt < 3; ++gt)                                            \
        acc[gt] = __builtin_amdgcn_mfma_i32_16x16x64_i8(wr[ks * 3 + gt], hf, acc[gt], 0, 0, 0); \
    }                                                                           \
    unsigned pk = 0;                                                            \
    _Pragma("unroll")                                                           \
    for (int r = 0; r < 4; ++r) {                                               \
      unsigned x0 = (r < 2) ? BUF[0].x : BUF[0].y;                              \
      unsigned x1 = (r < 2) ? BUF[1].x : BUF[1].y;                              \
      unsigned x2 = (r < 2) ? BUF[2].x : BUF[2].y;                              \
      float ir  = (r & 1) ? bfhi(x0) : bflo(x0);                                \
      float iz  = (r & 1) ? bfhi(x1) : bflo(x1);                                \
      float in_ = (r & 1) ? bfhi(x2) : bflo(x2);                                \
      float aR = fmaf((float)acc[0][r], f_[0], ir);                             \
      float rg = rcp_(1.0f + ex2_(aR));                                         \
      float aZ = fmaf((float)acc[1][r], f_[1], iz);                             \
      float zg = rcp_(1.0f + ex2_(aZ));                                         \
      float tN = fmaf((float)acc[2][r], f_[2], bhn[r]);                         \
      float aN = fmaf(rg, tN, in_);                                             \
      float ng = fmaf(2.0f, rcp_(1.0f + ex2_(aN)), -1.0f);                      \
      float h = ng + zg * (hprev[r] - ng);                                      \
      hprev[r] = h;                                                             \
      unsigned byte = __float_as_uint(fmaf(h, 127.0f, 12582912.0f)) & 0xffu;    \
      pk |= byte << (8 * r);                                                    \
    }                                                                           \
    *(unsigned*)&hl[(cur ^ 1) * GRU_HB + l15 * GRU_HST + w16 * 16 + lq * 4] = pk; \
    GI_LOAD(BUF, (S) + 2);                                                      \
    asm volatile("s_waitcnt lgkmcnt(0)\n\ts_barrier" ::: "memory");             \
    if (ys_i8) {                                                                \
      unsigned v = *(const unsigned*)&hl[(cur ^ 1) * GRU_HB + yrow * GRU_HST + ycol]; \
      *(unsigned*)&ys_i8[(((size_t)(b0 + yrow) * 256 + t) * 512) + dir * 256 + ycol] = v; \
    }                                                                           \
    cur ^= 1;                                                                   \
  } while (0)

  for (int s = 0; s < 256; s += 2) {
    GRU_STEP(s, gA);
    GRU_STEP(s + 1, gB);
  }

  if (!ys_i8) {
    #pragma unroll
    for (int r = 0; r < 4; ++r)
      out_final[(size_t)(b0 + l15) * 512 + (dir ? 0 : 256) + w16 * 16 + lq * 4 + r]
          = hprev[r];
  }
  #undef GRU_STEP
  #undef GI_LOAD
}

// ---------------------------------------------------------------------------
extern "C" void kernel_launch(void* const* d_in, const int* in_sizes, int n_in,
                              void* d_out, int out_size, void* d_ws, size_t ws_size,
                              hipStream_t stream) {
  (void)in_sizes; (void)n_in; (void)out_size; (void)ws_size;
  const float* c  = (const float*)d_in[0];
  const float* q  = (const float*)d_in[1];
  const float* Ws = (const float*)d_in[4];
  const float* w_ih[4] = { (const float*)d_in[5], (const float*)d_in[8],
                           (const float*)d_in[11], (const float*)d_in[14] };
  const float* w_hh[4] = { (const float*)d_in[6], (const float*)d_in[9],
                           (const float*)d_in[12], (const float*)d_in[15] };
  const float* b_l[4]  = { (const float*)d_in[7], (const float*)d_in[10],
                           (const float*)d_in[13], (const float*)d_in[16] };
  const int Kin[4] = {2048, 512, 2560, 512};

  static int lds_set = 0;
  if (!lds_set) {
    hipFuncSetAttribute((const void*)gemm_bt,
                        hipFuncAttributeMaxDynamicSharedMemorySize, GEMM_LDS_BYTES);
    lds_set = 1;
  }

  char* ws = (char*)d_ws;
  size_t off = 0;
  auto alloc = [&](size_t bytes) -> void* {
    void* p = ws + off; off += (bytes + 255) & ~(size_t)255; return p;
  };
  __bf16* Gbuf = (__bf16*)alloc((size_t)16384 * 2560 * 2);  // [G | M] bf16
  __bf16* gi   = (__bf16*)alloc((size_t)16384 * 1536 * 2);  // r'''-packed bf16
  __bf16* m0   = (__bf16*)alloc((size_t)16384 * 512 * 2);
  __bf16* r0   = (__bf16*)alloc((size_t)16384 * 512 * 2);
  signed char* ys8 = (signed char*)alloc((size_t)16384 * 512);
  __bf16* wihp[4]; signed char* wqp[4]; float* bihp[4]; float* swsp[4];
  for (int l = 0; l < 4; ++l) {
    wihp[l] = (__bf16*)alloc((size_t)1536 * Kin[l] * 2);
    wqp[l]  = (signed char*)alloc((size_t)1536 * 256);
    bihp[l] = (float*)alloc(1536 * 4);
    swsp[l] = (float*)alloc(96 * 4);
  }
  float* e_g  = (float*)alloc(4096 * 4);
  float* a_g  = (float*)alloc(16384 * 4);
  float* smax = (float*)alloc(16384 * 4);

  for (int l = 0; l < 4; ++l) {
    prep_wih<<<1536, 256, 0, stream>>>(w_ih[l], b_l[l], Kin[l], wihp[l], bihp[l]);
    prep_whh<<<96, 256, 0, stream>>>(w_hh[l], wqp[l], swsp[l]);
  }
  k_dots<<<5120, 256, 0, stream>>>(c, q, Ws, a_g, e_g);
  k_att_main<<<dim3(2, 64), 512, 0, stream>>>(c, q, Ws, a_g, e_g, smax, Gbuf);
  k_att_tail<<<64, 256, 0, stream>>>(c, smax, Gbuf);

  // layer mod0: G(2048) -> m0
  gemm_bt<<<dim3(64, 12), 512, GEMM_LDS_BYTES, stream>>>(Gbuf, 2560, wihp[0], bihp[0], gi, 2048);
  gru_rec<<<dim3(4, 2), 1024, 0, stream>>>(gi, wqp[0], swsp[0], b_l[0], ys8, nullptr);
  k_deq<<<4096, 256, 0, stream>>>(ys8, m0, 512);
  // layer mod1: m0(512) -> M (into Gbuf cols 2048:2560)
  gemm_bt<<<dim3(64, 12), 512, GEMM_LDS_BYTES, stream>>>(m0, 512, wihp[1], bihp[1], gi, 512);
  gru_rec<<<dim3(4, 2), 1024, 0, stream>>>(gi, wqp[1], swsp[1], b_l[1], ys8, nullptr);
  k_deq<<<4096, 256, 0, stream>>>(ys8, Gbuf + 2048, 2560);
  // layer rep0: [G|M](2560) -> r0
  gemm_bt<<<dim3(64, 12), 512, GEMM_LDS_BYTES, stream>>>(Gbuf, 2560, wihp[2], bihp[2], gi, 2560);
  gru_rec<<<dim3(4, 2), 1024, 0, stream>>>(gi, wqp[2], swsp[2], b_l[2], ys8, nullptr);
  k_deq<<<4096, 256, 0, stream>>>(ys8, r0, 512);
  // layer rep1: r0(512) -> final h only
  gemm_bt<<<dim3(64, 12), 512, GEMM_LDS_BYTES, stream>>>(r0, 512, wihp[3], bihp[3], gi, 512);
  gru_rec<<<dim3(4, 2), 1024, 0, stream>>>(gi, wqp[3], swsp[3], b_l[3], nullptr, (float*)d_out);
}